// Round 5
// baseline (430.652 us; speedup 1.0000x reference)
//
#include <hip/hip_runtime.h>

// SingleAttention: B=16, S=2048, F=512, D_K=D_V=512, fp32 in/out.
// q = xq@Wq+bq; k = xk@Wk+bk; v = xv@Wv+bv; out = softmax(q k^T / sqrt(512)) v
//
// Pipeline:
//  1) wt_kernel:  WT_z[n][k] = (f16)W_z[k][n]
//  2) proj_kernel: f16 MFMA GEMM 128x128 tile, BK=32, fused fp32->f16 staging.
//       z=0: Q[s][d] (pre-scaled by 1/sqrt(512)), z=1: K[s][d], z=2: Vt[b][d][s]
//  3) attn_kernel v5: flash attention, 8 waves, KVBLK=32, d-sliced PV.
//       - QK: wave w owns q-rows [16w,16w+16); K tile double-buffered in LDS
//         with a block-transpose slot permutation (slot = u*64 + g*16 + r):
//         staging is fully coalesced AND reads are base+lane*16+imm
//         (1KB contiguous per wave-read -> provably conflict-free).
//       - softmax: per-owner-wave, defer-max (THR=6); P[128][40] f16, al[128],
//         l[128] shared via LDS.
//       - PV: wave w owns d-slice [64w,64w+64) for ALL 128 q-rows; V fragments
//         read directly from global Vt (4 x 16B per iter, issued early, L2-hit)
//         -> V's 8x wave LDS amplification eliminated entirely.

typedef _Float16 f16_t;
typedef _Float16 f16x8 __attribute__((ext_vector_type(8)));
typedef _Float16 f16x4 __attribute__((ext_vector_type(4)));
typedef float f32x4 __attribute__((ext_vector_type(4)));

#define MFMA16(a, b, c) __builtin_amdgcn_mfma_f32_16x16x32_f16((a), (b), (c), 0, 0, 0)

__device__ __forceinline__ void gload_lds16(const void* gsrc, void* ldst) {
    __builtin_amdgcn_global_load_lds(
        (const __attribute__((address_space(1))) unsigned int*)gsrc,
        (__attribute__((address_space(3))) unsigned int*)ldst,
        16, 0, 0);
}

// ---------------- 1) weight transpose + f16 convert ----------------
__global__ __launch_bounds__(256) void wt_kernel(
    const float* __restrict__ Wq, const float* __restrict__ Wk, const float* __restrict__ Wv,
    f16_t* __restrict__ WTq, f16_t* __restrict__ WTk, f16_t* __restrict__ WTv)
{
    int idx = blockIdx.x * 256 + threadIdx.x;
    int z = idx >> 18;
    int r = idx & ((1 << 18) - 1);
    int k = r >> 9;
    int n = r & 511;
    const float* W = (z == 0) ? Wq : (z == 1) ? Wk : Wv;
    f16_t* WT = (z == 0) ? WTq : (z == 1) ? WTk : WTv;
    WT[(long)n * 512 + k] = (f16_t)W[(long)k * 512 + n];
}

// ---------------- 2) projection GEMM ----------------
__global__ __launch_bounds__(256) void proj_kernel(
    const float* __restrict__ xq, const float* __restrict__ xk, const float* __restrict__ xv,
    const f16_t* __restrict__ WTq, const f16_t* __restrict__ WTk, const f16_t* __restrict__ WTv,
    const float* __restrict__ bq, const float* __restrict__ bk, const float* __restrict__ bv,
    f16_t* __restrict__ Qo, f16_t* __restrict__ Ko, f16_t* __restrict__ Vto)
{
    __shared__ f16_t As[128 * 32];
    __shared__ f16_t Bs[128 * 32];

    const int z = blockIdx.z;
    const int bx = blockIdx.x;
    const int tid = threadIdx.x;
    const int lane = tid & 63;
    const int w = tid >> 6;
    const int g = lane >> 4, cc = lane & 15;
    const int wr = w >> 1, wc = w & 1;

    const float* Af = nullptr; const f16_t* Ah = nullptr;
    const float* Bf = nullptr; const f16_t* Bh = nullptr;
    const float* bias;
    long m0, n0;
    if (z == 0)      { Af = xq;  Bh = WTq; bias = bq; m0 = (long)(bx >> 2) * 128; n0 = (long)(bx & 3) * 128; }
    else if (z == 1) { Af = xk;  Bh = WTk; bias = bk; m0 = (long)(bx >> 2) * 128; n0 = (long)(bx & 3) * 128; }
    else             { Ah = WTv; Bf = xv;  bias = bv; m0 = (long)(bx & 3) * 128; n0 = (long)(bx >> 2) * 128; }

    f32x4 acc[4][4];
    #pragma unroll
    for (int i = 0; i < 4; ++i)
        #pragma unroll
        for (int j = 0; j < 4; ++j) acc[i][j] = (f32x4){0.f, 0.f, 0.f, 0.f};

    for (int k0 = 0; k0 < 512; k0 += 32) {
        __syncthreads();
        if (Af) {
            #pragma unroll
            for (int it = 0; it < 4; ++it) {
                int ci = tid + it * 256;
                int row = ci >> 3, col = (ci & 7) << 2;
                f32x4 v = *(const f32x4*)(Af + (m0 + row) * 512 + k0 + col);
                f16x4 h; h[0] = (f16_t)v[0]; h[1] = (f16_t)v[1]; h[2] = (f16_t)v[2]; h[3] = (f16_t)v[3];
                *(f16x4*)&As[row * 32 + col] = h;
            }
            #pragma unroll
            for (int it = 0; it < 2; ++it) {
                int ci = tid + it * 256;
                int row = ci >> 2, col = (ci & 3) << 3;
                *(f16x8*)&Bs[row * 32 + col] = *(const f16x8*)(Bh + (n0 + row) * 512 + k0 + col);
            }
        } else {
            #pragma unroll
            for (int it = 0; it < 2; ++it) {
                int ci = tid + it * 256;
                int row = ci >> 2, col = (ci & 3) << 3;
                *(f16x8*)&As[row * 32 + col] = *(const f16x8*)(Ah + (m0 + row) * 512 + k0 + col);
            }
            #pragma unroll
            for (int it = 0; it < 4; ++it) {
                int ci = tid + it * 256;
                int row = ci >> 3, col = (ci & 7) << 2;
                f32x4 v = *(const f32x4*)(Bf + (n0 + row) * 512 + k0 + col);
                f16x4 h; h[0] = (f16_t)v[0]; h[1] = (f16_t)v[1]; h[2] = (f16_t)v[2]; h[3] = (f16_t)v[3];
                *(f16x4*)&Bs[row * 32 + col] = h;
            }
        }
        __syncthreads();

        f16x8 a[4], bb[4];
        #pragma unroll
        for (int mt = 0; mt < 4; ++mt) a[mt] = *(const f16x8*)&As[(wr * 64 + mt * 16 + cc) * 32 + g * 8];
        #pragma unroll
        for (int nt = 0; nt < 4; ++nt) bb[nt] = *(const f16x8*)&Bs[(wc * 64 + nt * 16 + cc) * 32 + g * 8];
        #pragma unroll
        for (int mt = 0; mt < 4; ++mt)
            #pragma unroll
            for (int nt = 0; nt < 4; ++nt)
                acc[mt][nt] = MFMA16(a[mt], bb[nt], acc[mt][nt]);
    }

    if (z < 2) {
        f16_t* out = (z == 0) ? Qo : Ko;
        // fold attention scale 1/sqrt(512) into Q
        const float osc = (z == 0) ? 0.044194173824159216f : 1.0f;
        #pragma unroll
        for (int nt = 0; nt < 4; ++nt) {
            float bval = bias[n0 + wc * 64 + nt * 16 + cc];
            #pragma unroll
            for (int mt = 0; mt < 4; ++mt)
                #pragma unroll
                for (int i = 0; i < 4; ++i) {
                    long m = m0 + wr * 64 + mt * 16 + 4 * g + i;
                    long n = n0 + wc * 64 + nt * 16 + cc;
                    out[m * 512 + n] = (f16_t)((acc[mt][nt][i] + bval) * osc);
                }
        }
    } else {
        #pragma unroll
        for (int mt = 0; mt < 4; ++mt)
            #pragma unroll
            for (int i = 0; i < 4; ++i) {
                long m = m0 + wr * 64 + mt * 16 + 4 * g + i;   // d index
                float bval = bias[m];
                #pragma unroll
                for (int nt = 0; nt < 4; ++nt) {
                    long sg = n0 + wc * 64 + nt * 16 + cc;
                    long bidx = sg >> 11, sl = sg & 2047;
                    Vto[bidx * (512L * 2048) + m * 2048 + sl] = (f16_t)(acc[mt][nt][i] + bval);
                }
            }
    }
}

// ---------------- 3) flash attention v5 ----------------
// K LDS (per 32KB buffer), 16B slot index s:
//   region = s>>10 (kv rows 0-15 / 16-31), u = (s>>6)&15, gg = (s>>4)&3, r = s&15
//   content: K[kv = region*16 + r][d-chunk 4u+gg]
//   staging instr (w,it): slots [(4w+it)*64, +64), lane -> source
//     row = ((4w+it)>>4)*16 + (lane&15), chunk = 4*((4w+it)&15) + (lane>>4)
//     -> 16 dense 64B lines per instr (coalesced)
//   QK read (lane = g*16+cc): slot = region*1024 + u*64 + lane
//     -> addr = base + lane*16 + (u*1024 + region*16384)  [contiguous 1KB/read]
__global__ __launch_bounds__(512, 2) void attn_kernel(
    const f16_t* __restrict__ Q, const f16_t* __restrict__ K,
    const f16_t* __restrict__ Vt, float* __restrict__ out)
{
    extern __shared__ __align__(16) char smem[];
    char* KsB = smem;                              // [2][32768] K tiles
    f16_t* PlB = (f16_t*)(smem + 65536);           // [128][40] P (f16)
    float* al_s = (float*)(smem + 75776);          // [128] rescale factors
    float* l_s  = (float*)(smem + 76288);          // [128] final denominators
    unsigned* chg_s = (unsigned*)(smem + 76800);   // [8] per-wave chg flags

    const int tid = threadIdx.x;
    const int w = tid >> 6, lane = tid & 63;
    const int g = lane >> 4, cc = lane & 15;
    // XCD-aware swizzle: 256 blocks, 8 XCDs -> each XCD owns 2 full batches
    const int bx = (blockIdx.x & 7) * 32 + (blockIdx.x >> 3);
    const int b = bx >> 4, bt = bx & 15;
    const long qrow = (long)b * 2048 + bt * 128 + w * 16;

    // Q fragments (plain order), Q pre-scaled by 1/sqrt(512)
    f16x8 qf[16];
    {
        const f16_t* qp = Q + (qrow + cc) * 512;
        #pragma unroll
        for (int u = 0; u < 16; ++u) qf[u] = *(const f16x8*)(qp + u * 32 + g * 8);
    }

    // O: all 128 q-rows x this wave's 64-wide d-slice
    f32x4 O[8][4];
    #pragma unroll
    for (int qt = 0; qt < 8; ++qt)
        #pragma unroll
        for (int nt = 0; nt < 4; ++nt) O[qt][nt] = (f32x4){0.f, 0.f, 0.f, 0.f};
    float m_[4], l_[4];
    #pragma unroll
    for (int i = 0; i < 4; ++i) { m_[i] = -__builtin_inff(); l_[i] = 0.f; }

    const f16_t* Kb = K + (long)b * 2048 * 512;
    // V d-slice rows [64w, 64w+64): lane reads row 64w + nt*16 + cc at kv0 + g*8
    const f16_t* vsrc = Vt + (long)b * 512 * 2048 + (long)(w * 64 + cc) * 2048 + g * 8;

    // K staging sources (coalesced; see header comment)
    const f16_t* ksrc[4];
    #pragma unroll
    for (int it = 0; it < 4; ++it) {
        int si = 4 * w + it;
        int row = (si >> 4) * 16 + (lane & 15);
        int chunk = 4 * (si & 15) + (lane >> 4);
        ksrc[it] = Kb + (long)row * 512 + chunk * 8;
    }
    const int kdst = (4 * w) * 1024;   // wave-uniform LDS dest base (bytes)

    // prologue: stage K tile 0 into buf 0
    #pragma unroll
    for (int it = 0; it < 4; ++it) {
        gload_lds16(ksrc[it], KsB + kdst + it * 1024);
        ksrc[it] += 32 * 512;
    }
    asm volatile("s_waitcnt vmcnt(0)" ::: "memory");
    __syncthreads();

    int cur = 0;
    for (int t = 0; t < 64; ++t) {
        // issue next K tile (async, other buffer) BEFORE compute
        if (t < 63) {
            char* kd = KsB + (cur ^ 1) * 32768 + kdst;
            #pragma unroll
            for (int it = 0; it < 4; ++it) {
                gload_lds16(ksrc[it], kd + it * 1024);
                ksrc[it] += 32 * 512;
            }
        }
        // issue V fragment loads for THIS tile (consumed after barrier1;
        // HBM/L2 latency hides under QK + softmax)
        f16x8 vf0 = *(const f16x8*)(vsrc);
        f16x8 vf1 = *(const f16x8*)(vsrc + 32768);
        f16x8 vf2 = *(const f16x8*)(vsrc + 65536);
        f16x8 vf3 = *(const f16x8*)(vsrc + 98304);
        vsrc += 32;

        // QK: S[16 q][32 kv], contiguous conflict-free K reads
        const char* Kc = KsB + cur * 32768 + lane * 16;
        f32x4 s0 = (f32x4){0.f, 0.f, 0.f, 0.f}, s1 = (f32x4){0.f, 0.f, 0.f, 0.f};
        __builtin_amdgcn_s_setprio(1);
        #pragma unroll
        for (int u = 0; u < 16; ++u) {
            f16x8 k0 = *(const f16x8*)(Kc + u * 1024);
            f16x8 k1 = *(const f16x8*)(Kc + u * 1024 + 16384);
            s0 = MFMA16(qf[u], k0, s0);
            s1 = MFMA16(qf[u], k1, s1);
        }
        __builtin_amdgcn_s_setprio(0);

        // online softmax (owner wave); lane holds rows q=4g+i, col kv=cc (+16)
        float rmax[4];
        #pragma unroll
        for (int i = 0; i < 4; ++i) rmax[i] = fmaxf(s0[i], s1[i]);
        #pragma unroll
        for (int off = 1; off < 16; off <<= 1) {
            #pragma unroll
            for (int i = 0; i < 4; ++i)
                rmax[i] = fmaxf(rmax[i], __shfl_xor(rmax[i], off, 64));
        }
        // defer-max (T13): only raise running max when it grew by > 6
        float al[4]; bool chg = false;
        #pragma unroll
        for (int i = 0; i < 4; ++i) {
            bool upd = rmax[i] > m_[i] + 6.0f;
            al[i] = upd ? __expf(m_[i] - rmax[i]) : 1.0f;
            if (upd) m_[i] = rmax[i];
            chg = chg || upd;
        }
        float rs[4];
        #pragma unroll
        for (int i = 0; i < 4; ++i) {
            float e0 = __expf(s0[i] - m_[i]);
            float e1 = __expf(s1[i] - m_[i]);
            rs[i] = e0 + e1;
            PlB[(w * 16 + 4 * g + i) * 40 + cc]      = (f16_t)e0;
            PlB[(w * 16 + 4 * g + i) * 40 + 16 + cc] = (f16_t)e1;
        }
        #pragma unroll
        for (int off = 1; off < 16; off <<= 1) {
            #pragma unroll
            for (int i = 0; i < 4; ++i)
                rs[i] += __shfl_xor(rs[i], off, 64);
        }
        #pragma unroll
        for (int i = 0; i < 4; ++i) l_[i] = l_[i] * al[i] + rs[i];
        if (cc == 0) {
            #pragma unroll
            for (int i = 0; i < 4; ++i) al_s[w * 16 + 4 * g + i] = al[i];
        }
        bool chgAny = __any(chg);
        if (lane == 0) chg_s[w] = chgAny ? 1u : 0u;
        __syncthreads();   // barrier1: P, al, chg ready

        // block-wide rescale check
        unsigned anyc = chg_s[0] | chg_s[1] | chg_s[2] | chg_s[3]
                      | chg_s[4] | chg_s[5] | chg_s[6] | chg_s[7];
        if (anyc) {
            #pragma unroll
            for (int qt = 0; qt < 8; ++qt) {
                f32x4 av = *(const f32x4*)&al_s[qt * 16 + 4 * g];
                #pragma unroll
                for (int nt = 0; nt < 4; ++nt)
                    #pragma unroll
                    for (int i = 0; i < 4; ++i) O[qt][nt][i] *= av[i];
            }
        }

        // PV: A = P[q][kv] (LDS), B = V d-slice (global regs, already loaded)
        __builtin_amdgcn_s_setprio(1);
        #pragma unroll
        for (int qt = 0; qt < 8; ++qt) {
            f16x8 pf = *(const f16x8*)&PlB[(qt * 16 + cc) * 40 + g * 8];
            O[qt][0] = MFMA16(pf, vf0, O[qt][0]);
            O[qt][1] = MFMA16(pf, vf1, O[qt][1]);
            O[qt][2] = MFMA16(pf, vf2, O[qt][2]);
            O[qt][3] = MFMA16(pf, vf3, O[qt][3]);
        }
        __builtin_amdgcn_s_setprio(0);

        asm volatile("s_waitcnt vmcnt(0)" ::: "memory");
        __syncthreads();   // barrier2: K(t+1) staged; P reads done
        cur ^= 1;
    }

    // share denominators, then write O-slice
    if (cc == 0) {
        #pragma unroll
        for (int i = 0; i < 4; ++i) l_s[w * 16 + 4 * g + i] = l_[i];
    }
    __syncthreads();

    float* ob = out + ((long)b * 2048 + bt * 128) * 512;
    #pragma unroll
    for (int qt = 0; qt < 8; ++qt) {
        f32x4 lv = *(const f32x4*)&l_s[qt * 16 + 4 * g];
        float inv[4];
        #pragma unroll
        for (int i = 0; i < 4; ++i) inv[i] = 1.0f / lv[i];
        #pragma unroll
        for (int nt = 0; nt < 4; ++nt)
            #pragma unroll
            for (int i = 0; i < 4; ++i)
                ob[(long)(qt * 16 + 4 * g + i) * 512 + w * 64 + nt * 16 + cc] = O[qt][nt][i] * inv[i];
    }
}

// ---------------- launch ----------------
extern "C" void kernel_launch(void* const* d_in, const int* in_sizes, int n_in,
                              void* d_out, int out_size, void* d_ws, size_t ws_size,
                              hipStream_t stream)
{
    (void)in_sizes; (void)n_in; (void)out_size; (void)ws_size;
    const float* xq = (const float*)d_in[0];
    const float* xk = (const float*)d_in[1];
    const float* xv = (const float*)d_in[2];
    const float* Wq = (const float*)d_in[3];
    const float* bq = (const float*)d_in[4];
    const float* Wk = (const float*)d_in[5];
    const float* bk = (const float*)d_in[6];
    const float* Wv = (const float*)d_in[7];
    const float* bv = (const float*)d_in[8];
    float* out = (float*)d_out;

    f16_t* ws = (f16_t*)d_ws;
    f16_t* WTq = ws;
    f16_t* WTk = WTq + 512L * 512;
    f16_t* WTv = WTk + 512L * 512;
    f16_t* Qb  = WTv + 512L * 512;
    f16_t* Kb  = Qb + 32768L * 512;
    f16_t* Vtb = Kb + 32768L * 512;

    wt_kernel<<<3072, 256, 0, stream>>>(Wq, Wk, Wv, WTq, WTk, WTv);

    dim3 pgrid(1024, 1, 3);
    proj_kernel<<<pgrid, 256, 0, stream>>>(xq, xk, xv, WTq, WTk, WTv,
                                           bq, bk, bv, Qb, Kb, Vtb);

    // dynamic LDS: 2x32KB K + 10.25KB P + al/l/chg = 76832 B
    attn_kernel<<<256, 512, 76832, stream>>>(Qb, Kb, Vtb, out);
}